// Round 1
// 179.873 us; speedup vs baseline: 1.0861x; 1.0861x over previous
//
#include <hip/hip_runtime.h>
#include <hip/hip_bf16.h>
#include <stdint.h>

typedef short bf16x8 __attribute__((ext_vector_type(8)));
typedef float f32x4 __attribute__((ext_vector_type(4)));

__device__ __forceinline__ unsigned short f2bf(float f) {
  union { float f; unsigned int u; } v;
  v.f = f;
  unsigned int u = v.u;
  u = (u + 0x7fffu + ((u >> 16) & 1u)) >> 16;  // RNE
  return (unsigned short)u;
}

__device__ __forceinline__ unsigned int pack_bf16(float x, float y) {
  return (unsigned int)f2bf(x) | ((unsigned int)f2bf(y) << 16);
}

typedef union { bf16x8 v; unsigned int u[4]; } frag_u;

// global->LDS async copy, 16B per lane.
__device__ __forceinline__ void gload16(const void* g, void* lds) {
  __builtin_amdgcn_global_load_lds(
      (const __attribute__((address_space(1))) unsigned int*)(unsigned long long)g,
      (__attribute__((address_space(3))) unsigned int*)(unsigned long long)(unsigned)(unsigned long long)lds,
      16, 0, 0);
}

__device__ __forceinline__ bf16x8 lds_frag(const unsigned short* t, int row, int ch4q) {
  return *(const bf16x8*)(t + row * 64 + ((ch4q ^ (row & 7)) << 3));
}

// Fragment layouts (element = short unless noted):
//  Qfrag/Kfrag[b][t16][h][sub][lane]: ((b*64+t16)*8192) + h*1024 + sub*512 + lane*8
//  Vfrag PAIRED [b][h][ktp][dm][lane][8]: (b*8+h)*65536 + (ktp*4+dm)*512 + lane*8
//  Mfrag (u32) PAIRED [b][qt][ktp][lane][2]: (b*64+qt)*4096 + ktp*128 + lane*2 + half
//  Zinv  [b][qt][h][q]: ((b*64+qt)*8+h)*16 + q   (precomputed 1/Z)

// ---------------------------------------------------------------------------
// Kernel 1: prep — x -> bf16, 7 weights -> transposed bf16 (Wt[n][k] = W[k][n])
// ---------------------------------------------------------------------------
__global__ __launch_bounds__(256) void prep_kernel(
    const float* __restrict__ x,
    const float* __restrict__ Wq, const float* __restrict__ Wk, const float* __restrict__ Wv,
    const float* __restrict__ Wfh, const float* __restrict__ Wfg,
    const float* __restrict__ Wrh, const float* __restrict__ Wrg,
    unsigned short* __restrict__ xb, unsigned short* __restrict__ wt) {
  int bid = blockIdx.x;
  int tid = threadIdx.x;
  if (bid < 448) {
    __shared__ float tile[64][65];
    int mat = bid >> 6;
    int t = bid & 63;
    int tr = (t >> 3) * 64, tc = (t & 7) * 64;
    const float* W = (mat == 0) ? Wq : (mat == 1) ? Wk : (mat == 2) ? Wv
                   : (mat == 3) ? Wfh : (mat == 4) ? Wfg : (mat == 5) ? Wrh : Wrg;
    unsigned short* Wt = wt + (size_t)mat * 512 * 512;
    for (int rep = 0; rep < 16; rep++) {
      int idx = rep * 256 + tid;
      int r = idx >> 6, c = idx & 63;
      tile[r][c] = W[(tr + r) * 512 + tc + c];
    }
    __syncthreads();
    for (int rep = 0; rep < 16; rep++) {
      int idx = rep * 256 + tid;
      int r = idx >> 6, c = idx & 63;
      Wt[(tc + r) * 512 + tr + c] = f2bf(tile[c][r]);
    }
  } else {
    int blk = bid - 448;
    const float4* xi = (const float4*)x;
    for (int rep = 0; rep < 32; rep++) {
      int i = blk * 256 + tid + rep * 16384;
      float4 v = xi[i];
      unsigned int lo = (unsigned int)f2bf(v.x) | ((unsigned int)f2bf(v.y) << 16);
      unsigned int hi = (unsigned int)f2bf(v.z) | ((unsigned int)f2bf(v.w) << 16);
      uint2 u; u.x = lo; u.y = hi;
      *(uint2*)&xb[(size_t)i * 4] = u;
    }
  }
}

// ---------------------------------------------------------------------------
// Kernel 2: QKV projection, LDS-staged GEMM; epilogue emits fragment layouts
// (Qfrag/Kfrag, pair-packed Vfrag). grid (8 nb = head, 64 mt), 256 threads.
// ---------------------------------------------------------------------------
__global__ __launch_bounds__(256, 2) void qkv_kernel(
    const unsigned short* __restrict__ xb,
    const unsigned short* __restrict__ wtq, const unsigned short* __restrict__ wtk,
    const unsigned short* __restrict__ wtv,
    const float* __restrict__ bq, const float* __restrict__ bk, const float* __restrict__ bv,
    unsigned short* __restrict__ Qfrag, unsigned short* __restrict__ Kfrag,
    unsigned short* __restrict__ Vfrag) {
  __shared__ unsigned short As[64 * 64];
  __shared__ unsigned short Bq[64 * 64];
  __shared__ unsigned short Bk[64 * 64];
  __shared__ unsigned short Bv[64 * 64];
  __shared__ __attribute__((aligned(16))) unsigned short st[3][64 * 72];
  const int m0 = blockIdx.y * 64, n0 = blockIdx.x * 64;
  const int tid = threadIdx.x, w = tid >> 6, lane = tid & 63;
  const int c = lane & 15, quad = lane >> 4;
  const int wm = w & 1, wn = w >> 1;
  const int rsel = lane >> 3, csel = lane & 7;
  const int sc = csel ^ rsel;
  const char* Ag  = (const char*)xb  + (size_t)(m0 + w * 16 + rsel) * 1024 + sc * 16;
  const char* Bgq = (const char*)wtq + (size_t)(n0 + w * 16 + rsel) * 1024 + sc * 16;
  const char* Bgk = (const char*)wtk + (size_t)(n0 + w * 16 + rsel) * 1024 + sc * 16;
  const char* Bgv = (const char*)wtv + (size_t)(n0 + w * 16 + rsel) * 1024 + sc * 16;
  unsigned short* lA = &As[w * 1024];
  unsigned short* lQ = &Bq[w * 1024];
  unsigned short* lK = &Bk[w * 1024];
  unsigned short* lV = &Bv[w * 1024];

  f32x4 acc[3][2][2];
  f32x4 z4 = {0.f, 0.f, 0.f, 0.f};
#pragma unroll
  for (int o = 0; o < 3; o++)
#pragma unroll
    for (int i = 0; i < 2; i++)
#pragma unroll
      for (int j = 0; j < 2; j++) acc[o][i][j] = z4;

  for (int ks = 0; ks < 8; ks++) {
    if (ks) __syncthreads();
    const int kb = ks * 128;
    gload16(Ag + kb, lA);        gload16(Ag + kb + 8192, lA + 512);
    gload16(Bgq + kb, lQ);       gload16(Bgq + kb + 8192, lQ + 512);
    gload16(Bgk + kb, lK);       gload16(Bgk + kb + 8192, lK + 512);
    gload16(Bgv + kb, lV);       gload16(Bgv + kb + 8192, lV + 512);
    __syncthreads();
#pragma unroll
    for (int ch = 0; ch < 2; ch++) {
      const int cq = ch * 4 + quad;
      bf16x8 a0 = lds_frag(As, wm * 32 + c, cq);
      bf16x8 a1 = lds_frag(As, wm * 32 + 16 + c, cq);
#pragma unroll
      for (int nt = 0; nt < 2; nt++) {
        const int rb = wn * 32 + nt * 16 + c;
        bf16x8 fq = lds_frag(Bq, rb, cq);
        bf16x8 fk = lds_frag(Bk, rb, cq);
        bf16x8 fv = lds_frag(Bv, rb, cq);
        acc[0][0][nt] = __builtin_amdgcn_mfma_f32_16x16x32_bf16(a0, fq, acc[0][0][nt], 0, 0, 0);
        acc[0][1][nt] = __builtin_amdgcn_mfma_f32_16x16x32_bf16(a1, fq, acc[0][1][nt], 0, 0, 0);
        acc[1][0][nt] = __builtin_amdgcn_mfma_f32_16x16x32_bf16(a0, fk, acc[1][0][nt], 0, 0, 0);
        acc[1][1][nt] = __builtin_amdgcn_mfma_f32_16x16x32_bf16(a1, fk, acc[1][1][nt], 0, 0, 0);
        acc[2][0][nt] = __builtin_amdgcn_mfma_f32_16x16x32_bf16(a0, fv, acc[2][0][nt], 0, 0, 0);
        acc[2][1][nt] = __builtin_amdgcn_mfma_f32_16x16x32_bf16(a1, fv, acc[2][1][nt], 0, 0, 0);
      }
    }
  }

  // stage: st[0]=Q[t][d], st[1]=K[t][d], st[2]=V[d][t]
#pragma unroll
  for (int ms = 0; ms < 2; ms++)
#pragma unroll
    for (int nt = 0; nt < 2; nt++) {
      int n_l = wn * 32 + nt * 16 + c;
      int n = n0 + n_l;
      float biasq = bq[n], biask = bk[n], biasv = bv[n];
#pragma unroll
      for (int r = 0; r < 4; r++) {
        int m_l = wm * 32 + ms * 16 + quad * 4 + r;
        st[0][m_l * 72 + n_l] = f2bf((acc[0][ms][nt][r] + biasq) * 0.125f);
        st[1][m_l * 72 + n_l] = f2bf(acc[1][ms][nt][r] + biask);
        st[2][n_l * 72 + m_l] = f2bf(acc[2][ms][nt][r] + biasv);
      }
    }
  __syncthreads();

  {
    const int h = n0 >> 6;
    const int bb = m0 >> 10, t0b = (m0 & 1023) >> 4;
#pragma unroll
    for (int sub = 0; sub < 2; sub++) {
      uint4 vq = *(uint4*)&st[0][(w * 16 + c) * 72 + sub * 32 + quad * 8];
      uint4 vk = *(uint4*)&st[1][(w * 16 + c) * 72 + sub * 32 + quad * 8];
      size_t base = (size_t)((bb * 64 + t0b + w) * 8192) + h * 1024 + sub * 512 + lane * 8;
      *(uint4*)&Qfrag[base] = vq;
      *(uint4*)&Kfrag[base] = vk;
    }
    // pair-packed V fragments: kt = t0b + w; half = kt&1 selects shorts 0..3/4..7
    const int ktq = t0b + w;
    const int ktp = ktq >> 1, half = ktq & 1;
#pragma unroll
    for (int dm = 0; dm < 4; dm++) {
      uint2 vv = *(uint2*)&st[2][(dm * 16 + c) * 72 + w * 16 + quad * 4];
      size_t base = (size_t)(bb * 8 + h) * 65536 + (size_t)(ktp * 4 + dm) * 512
                  + lane * 8 + half * 4;
      *(uint2*)&Vfrag[base] = vv;
    }
  }
}

// ---------------------------------------------------------------------------
// Kernel 3: zgate — FUSED softmax-denominator + gate mask (replaces the old
// zpass1+zpass2 pair: one QK^T pass instead of two).
// grid (4 b, 64 qt16), 512 thr = 8 waves; wave w owns kt = 8w..8w+7 (128 k).
// Per h: P = exp(s) held in registers across the in-LDS cross-wave Z
// reduction (2 barriers), then gate logit G += (cw[h]/Z)*P accumulated in
// 32 persistent VGPRs. Emits pair-packed Mfrag (same contract as before)
// and precomputed invZ for pv.
// ---------------------------------------------------------------------------
__global__ __launch_bounds__(512, 4) void zgate_kernel(
    const unsigned short* __restrict__ Qfrag, const unsigned short* __restrict__ Kfrag,
    const float* __restrict__ conv_w, const float* __restrict__ conv_b,
    unsigned int* __restrict__ Mfrag, float* __restrict__ Zinv) {
  const int b = blockIdx.x, qt = blockIdx.y;
  const int tid = threadIdx.x, w = tid >> 6, lane = tid & 63;
  const int c = lane & 15, quad = lane >> 4;
  __shared__ float zbuf[8][16];

  f32x4 z4 = {0.f, 0.f, 0.f, 0.f};
  const float cb = conv_b[0];
  const size_t qbase = (size_t)((b * 64 + qt) * 8192) + lane * 8;
  const int kt0 = w * 8;
  const size_t kb0 = (size_t)((b * 64 + kt0) * 8192) + lane * 8;

  f32x4 g[8];
#pragma unroll
  for (int j = 0; j < 8; j++) g[j] = {cb, cb, cb, cb};

  for (int h = 0; h < 8; h++) {
    bf16x8 qf0 = *(const bf16x8*)&Qfrag[qbase + h * 1024];
    bf16x8 qf1 = *(const bf16x8*)&Qfrag[qbase + h * 1024 + 512];
    f32x4 p[8];
    float zh = 0.f;
#pragma unroll
    for (int j = 0; j < 8; j++) {
      const size_t kb = kb0 + (size_t)j * 8192 + h * 1024;
      bf16x8 kf0 = *(const bf16x8*)&Kfrag[kb];
      bf16x8 kf1 = *(const bf16x8*)&Kfrag[kb + 512];
      f32x4 s = __builtin_amdgcn_mfma_f32_16x16x32_bf16(kf0, qf0, z4, 0, 0, 0);
      s = __builtin_amdgcn_mfma_f32_16x16x32_bf16(kf1, qf1, s, 0, 0, 0);
      p[j][0] = __expf(s[0]); p[j][1] = __expf(s[1]);
      p[j][2] = __expf(s[2]); p[j][3] = __expf(s[3]);
      zh += (p[j][0] + p[j][1]) + (p[j][2] + p[j][3]);
    }
    // wave-local rowsum over k (rows): lanes differing in bits 4/5 share q=c
    zh += __shfl_xor(zh, 16); zh += __shfl_xor(zh, 32);
    __syncthreads();                 // prev h's zbuf reads complete
    if (quad == 0) zbuf[w][c] = zh;
    __syncthreads();                 // all wave partials visible
    float Z = ((zbuf[0][c] + zbuf[1][c]) + (zbuf[2][c] + zbuf[3][c]))
            + ((zbuf[4][c] + zbuf[5][c]) + (zbuf[6][c] + zbuf[7][c]));
    const float izq = 1.0f / Z;
    const float cwz = conv_w[h] * izq;
    if (w == 0 && quad == 0)
      Zinv[(size_t)((b * 64 + qt) * 8 + h) * 16 + c] = izq;
#pragma unroll
    for (int j = 0; j < 8; j++) {
      g[j][0] += cwz * p[j][0]; g[j][1] += cwz * p[j][1];
      g[j][2] += cwz * p[j][2]; g[j][3] += cwz * p[j][3];
    }
  }

  // masks from sign(G): bit0 = M_f (logit<=0), bit1 = M_r (logit>=0);
  // pair-packed per ktp exactly as pv expects.
#pragma unroll
  for (int j = 0; j < 4; j++) {
    unsigned int p0 = 0, p1 = 0;
#pragma unroll
    for (int r = 0; r < 4; r++) {
      p0 |= ((g[2 * j][r] <= 0.f ? 1u : 0u) | (g[2 * j][r] >= 0.f ? 2u : 0u)) << (8 * r);
      p1 |= ((g[2 * j + 1][r] <= 0.f ? 1u : 0u) | (g[2 * j + 1][r] >= 0.f ? 2u : 0u)) << (8 * r);
    }
    const int ktp = w * 4 + j;
    uint2 mm; mm.x = p0; mm.y = p1;
    *(uint2*)&Mfrag[(size_t)(b * 64 + qt) * 4096 + (size_t)ktp * 128 + lane * 2] = mm;
  }
}

// ---------------------------------------------------------------------------
// Kernel 5: pv — grid (8 h, 128 = b*32+qb), 256 thr = 4 waves =
// (2 q-tiles x 2 k-halves) -> 4 blocks/CU, 16 waves/CU. Pair-packed K=32
// MFMAs; denominators via ones-row MFMA; phased LDS combine in the epilogue.
// ---------------------------------------------------------------------------
__global__ __launch_bounds__(256, 4) void pv_kernel(
    const unsigned short* __restrict__ Qfrag, const unsigned short* __restrict__ Kfrag,
    const unsigned short* __restrict__ Vfrag,
    const unsigned int* __restrict__ Mfrag, const float* __restrict__ Zinv,
    unsigned short* __restrict__ Tfb, unsigned short* __restrict__ Trb) {
  const int h = blockIdx.x;
  const int b = blockIdx.y >> 5, qb = blockIdx.y & 31;
  const int tid = threadIdx.x, w = tid >> 6, lane = tid & 63;
  const int c = lane & 15, quad = lane >> 4;
  const int qloc = w & 1, kh = w >> 1;
  const int qt = qb * 2 + qloc;

  __shared__ __attribute__((aligned(16))) float red[2][4][256][4];  // 32 KB, reused
  __shared__ float zb[2][2][16];

  f32x4 z4 = {0.f, 0.f, 0.f, 0.f};
  const size_t qbase = (size_t)((b * 64 + qt) * 8192) + h * 1024 + lane * 8;
  bf16x8 qf0 = *(const bf16x8*)&Qfrag[qbase];
  bf16x8 qf1 = *(const bf16x8*)&Qfrag[qbase + 512];
  const float invZ = Zinv[(size_t)((b * 64 + qt) * 8 + h) * 16 + c];
  const size_t mbase = (size_t)(b * 64 + qt) * 4096 + lane * 2;
  const size_t vb0 = (size_t)(b * 8 + h) * 65536 + lane * 8;

  frag_u ones;
  ones.u[0] = 0x3F803F80u; ones.u[1] = 0x3F803F80u;
  ones.u[2] = 0x3F803F80u; ones.u[3] = 0x3F803F80u;

  f32x4 accf[4], accr[4];
#pragma unroll
  for (int i = 0; i < 4; i++) { accf[i] = z4; accr[i] = z4; }
  f32x4 acc_zf = z4, acc_zr = z4;

#pragma unroll 2
  for (int ip = 0; ip < 16; ip++) {
    const int ktp = kh * 16 + ip;
    const int kta = ktp * 2, ktb = kta + 1;
    const size_t kba = (size_t)((b * 64 + kta) * 8192) + h * 1024 + lane * 8;
    const size_t kbb = (size_t)((b * 64 + ktb) * 8192) + h * 1024 + lane * 8;
    bf16x8 ka0 = *(const bf16x8*)&Kfrag[kba];
    bf16x8 ka1 = *(const bf16x8*)&Kfrag[kba + 512];
    bf16x8 kb0 = *(const bf16x8*)&Kfrag[kbb];
    bf16x8 kb1 = *(const bf16x8*)&Kfrag[kbb + 512];
    f32x4 sa = __builtin_amdgcn_mfma_f32_16x16x32_bf16(ka0, qf0, z4, 0, 0, 0);
    sa = __builtin_amdgcn_mfma_f32_16x16x32_bf16(ka1, qf1, sa, 0, 0, 0);
    f32x4 sb = __builtin_amdgcn_mfma_f32_16x16x32_bf16(kb0, qf0, z4, 0, 0, 0);
    sb = __builtin_amdgcn_mfma_f32_16x16x32_bf16(kb1, qf1, sb, 0, 0, 0);
    const uint2 mp = *(const uint2*)&Mfrag[mbase + (size_t)ktp * 128];
    float ea[4], eb[4];
#pragma unroll
    for (int r = 0; r < 4; r++) {
      ea[r] = __expf(__expf(sa[r]) * invZ);
      eb[r] = __expf(__expf(sb[r]) * invZ);
    }
    frag_u pF, pR;
    pF.u[0] = pack_bf16((mp.x & 0x1u) ? ea[0] : 1.f, (mp.x & 0x100u) ? ea[1] : 1.f);
    pF.u[1] = pack_bf16((mp.x & 0x10000u) ? ea[2] : 1.f, (mp.x & 0x1000000u) ? ea[3] : 1.f);
    pF.u[2] = pack_bf16((mp.y & 0x1u) ? eb[0] : 1.f, (mp.y & 0x100u) ? eb[1] : 1.f);
    pF.u[3] = pack_bf16((mp.y & 0x10000u) ? eb[2] : 1.f, (mp.y & 0x1000000u) ? eb[3] : 1.f);
    pR.u[0] = pack_bf16((mp.x & 0x2u) ? ea[0] : 1.f, (mp.x & 0x200u) ? ea[1] : 1.f);
    pR.u[1] = pack_bf16((mp.x & 0x20000u) ? ea[2] : 1.f, (mp.x & 0x2000000u) ? ea[3] : 1.f);
    pR.u[2] = pack_bf16((mp.y & 0x2u) ? eb[0] : 1.f, (mp.y & 0x200u) ? eb[1] : 1.f);
    pR.u[3] = pack_bf16((mp.y & 0x20000u) ? eb[2] : 1.f, (mp.y & 0x2000000u) ? eb[3] : 1.f);
    acc_zf = __builtin_amdgcn_mfma_f32_16x16x32_bf16(ones.v, pF.v, acc_zf, 0, 0, 0);
    acc_zr = __builtin_amdgcn_mfma_f32_16x16x32_bf16(ones.v, pR.v, acc_zr, 0, 0, 0);
#pragma unroll
    for (int dm = 0; dm < 4; dm++) {
      bf16x8 vf = *(const bf16x8*)&Vfrag[vb0 + (size_t)(ktp * 4 + dm) * 512];
      accf[dm] = __builtin_amdgcn_mfma_f32_16x16x32_bf16(vf, pF.v, accf[dm], 0, 0, 0);
      accr[dm] = __builtin_amdgcn_mfma_f32_16x16x32_bf16(vf, pR.v, accr[dm], 0, 0, 0);
    }
  }

  // ---- cross-kh combine (phased through the 32KB red buffer) ----
  if (kh == 1) {
#pragma unroll
    for (int dm = 0; dm < 4; dm++) *(f32x4*)red[qloc][dm][lane] = accf[dm];
    if (lane < 16) { zb[qloc][0][lane] = acc_zf[0]; zb[qloc][1][lane] = acc_zr[0]; }
  }
  __syncthreads();
  if (kh == 0) {
#pragma unroll
    for (int dm = 0; dm < 4; dm++) accf[dm] += *(f32x4*)red[qloc][dm][lane];
  }
  __syncthreads();
  if (kh == 1) {
#pragma unroll
    for (int dm = 0; dm < 4; dm++) *(f32x4*)red[qloc][dm][lane] = accr[dm];
  }
  __syncthreads();
  uint2 outf[4], outr[4];
  if (kh == 0) {
#pragma unroll
    for (int dm = 0; dm < 4; dm++) accr[dm] += *(f32x4*)red[qloc][dm][lane];
    const float zf = acc_zf[0] + zb[qloc][0][c];
    const float zr = acc_zr[0] + zb[qloc][1][c];
    const float izf = 1.0f / zf, izr = 1.0f / zr;
#pragma unroll
    for (int dm = 0; dm < 4; dm++) {
      outf[dm].x = pack_bf16(accf[dm][0] * izf, accf[dm][1] * izf);
      outf[dm].y = pack_bf16(accf[dm][2] * izf, accf[dm][3] * izf);
      outr[dm].x = pack_bf16(accr[dm][0] * izr, accr[dm][1] * izr);
      outr[dm].y = pack_bf16(accr[dm][2] * izr, accr[dm][3] * izr);
    }
  }
  __syncthreads();
  unsigned short* ts = (unsigned short*)red;  // 64 rows x 72 = 9.2 KB < 32 KB
  if (kh == 0) {
    const int qrow = qloc * 16 + c;
#pragma unroll
    for (int dm = 0; dm < 4; dm++) {
      *(uint2*)&ts[qrow * 72 + dm * 16 + quad * 4] = outf[dm];
      *(uint2*)&ts[(32 + qrow) * 72 + dm * 16 + quad * 4] = outr[dm];
    }
  }
  __syncthreads();
  {
    const int row = tid >> 3, seg = tid & 7;
    const size_t g = (size_t)(b * 1024 + qb * 32 + row) * 512 + h * 64 + seg * 8;
    *(uint4*)&Tfb[g] = *(uint4*)&ts[row * 72 + seg * 8];
    *(uint4*)&Trb[g] = *(uint4*)&ts[(32 + row) * 72 + seg * 8];
  }
}

// ---------------------------------------------------------------------------
// Kernel 6: final — LDS-staged fused 4-GEMM + gate combine.
// grid (8 nb, 128 mt32): 32m x 64n tiles, LDS 40 KB -> 4 blocks/CU.
// ---------------------------------------------------------------------------
__global__ __launch_bounds__(256, 4) void final_kernel(
    const unsigned short* __restrict__ Tfb, const unsigned short* __restrict__ Trb,
    const unsigned short* __restrict__ wfh, const unsigned short* __restrict__ wfg,
    const unsigned short* __restrict__ wrh, const unsigned short* __restrict__ wrg,
    const float* __restrict__ bfh, const float* __restrict__ bfg,
    const float* __restrict__ brh, const float* __restrict__ brg,
    float* __restrict__ out) {
  __shared__ unsigned short Atf[32 * 64];
  __shared__ unsigned short Atr[32 * 64];
  __shared__ unsigned short Bfh[64 * 64];
  __shared__ unsigned short Bfg[64 * 64];
  __shared__ unsigned short Brh[64 * 64];
  __shared__ unsigned short Brg[64 * 64];
  const int m0 = blockIdx.y * 32, n0 = blockIdx.x * 64;
  const int tid = threadIdx.x, w = tid >> 6, lane = tid & 63;
  const int c = lane & 15, quad = lane >> 4;
  const int wm = w & 1, wn = w >> 1;
  const int rsel = lane >> 3, csel = lane & 7;
  const int sc = csel ^ rsel;
  // A tiles: wave stages 8 rows (1 gload16); B tiles: 16 rows (2 gload16).
  const char* Agf = (const char*)Tfb + (size_t)(m0 + w * 8 + rsel) * 1024 + sc * 16;
  const char* Agr = (const char*)Trb + (size_t)(m0 + w * 8 + rsel) * 1024 + sc * 16;
  const char* Bg0 = (const char*)wfh + (size_t)(n0 + w * 16 + rsel) * 1024 + sc * 16;
  const char* Bg1 = (const char*)wfg + (size_t)(n0 + w * 16 + rsel) * 1024 + sc * 16;
  const char* Bg2 = (const char*)wrh + (size_t)(n0 + w * 16 + rsel) * 1024 + sc * 16;
  const char* Bg3 = (const char*)wrg + (size_t)(n0 + w * 16 + rsel) * 1024 + sc * 16;
  unsigned short* lAf = &Atf[w * 512];
  unsigned short* lAr = &Atr[w * 512];
  unsigned short* l0 = &Bfh[w * 1024];
  unsigned short* l1 = &Bfg[w * 1024];
  unsigned short* l2 = &Brh[w * 1024];
  unsigned short* l3 = &Brg[w * 1024];

  f32x4 acc[4][2];  // [mat][nt]
  f32x4 z4 = {0.f, 0.f, 0.f, 0.f};
#pragma unroll
  for (int o = 0; o < 4; o++)
#pragma unroll
    for (int j = 0; j < 2; j++) acc[o][j] = z4;

  for (int ks = 0; ks < 8; ks++) {
    if (ks) __syncthreads();
    const int kb = ks * 128;
    gload16(Agf + kb, lAf);
    gload16(Agr + kb, lAr);
    gload16(Bg0 + kb, l0);   gload16(Bg0 + kb + 8192, l0 + 512);
    gload16(Bg1 + kb, l1);   gload16(Bg1 + kb + 8192, l1 + 512);
    gload16(Bg2 + kb, l2);   gload16(Bg2 + kb + 8192, l2 + 512);
    gload16(Bg3 + kb, l3);   gload16(Bg3 + kb + 8192, l3 + 512);
    __syncthreads();
#pragma unroll
    for (int ch = 0; ch < 2; ch++) {
      const int cq = ch * 4 + quad;
      bf16x8 af = lds_frag(Atf, wm * 16 + c, cq);
      bf16x8 ar = lds_frag(Atr, wm * 16 + c, cq);
#pragma unroll
      for (int nt = 0; nt < 2; nt++) {
        const int rb = wn * 32 + nt * 16 + c;
        bf16x8 f0 = lds_frag(Bfh, rb, cq);
        bf16x8 f1 = lds_frag(Bfg, rb, cq);
        bf16x8 f2 = lds_frag(Brh, rb, cq);
        bf16x8 f3 = lds_frag(Brg, rb, cq);
        acc[0][nt] = __builtin_amdgcn_mfma_f32_16x16x32_bf16(af, f0, acc[0][nt], 0, 0, 0);
        acc[1][nt] = __builtin_amdgcn_mfma_f32_16x16x32_bf16(af, f1, acc[1][nt], 0, 0, 0);
        acc[2][nt] = __builtin_amdgcn_mfma_f32_16x16x32_bf16(ar, f2, acc[2][nt], 0, 0, 0);
        acc[3][nt] = __builtin_amdgcn_mfma_f32_16x16x32_bf16(ar, f3, acc[3][nt], 0, 0, 0);
      }
    }
  }

#pragma unroll
  for (int nt = 0; nt < 2; nt++) {
    int n = n0 + wn * 32 + nt * 16 + c;
    float b0 = bfh[n], b1 = bfg[n], b2 = brh[n], b3 = brg[n];
    int t0 = m0 + wm * 16 + quad * 4;
#pragma unroll
    for (int r = 0; r < 4; r++) {
      int t = t0 + r;
      float Ff = acc[0][nt][r] + b0;
      float Gf = 1.0f / (1.0f + __expf(-(acc[1][nt][r] + b1)));
      float Fr = acc[2][nt][r] + b2;
      float Gr = 1.0f / (1.0f + __expf(-(acc[3][nt][r] + b3)));
      float ef = __expf(Gf), er = __expf(Gr);
      out[(size_t)t * 512 + n] = (Ff * ef + Fr * er) / (ef + er);
    }
  }
}

// ---------------------------------------------------------------------------
// Launch. Workspace (bytes):
//   0: xb 4MB | 4: Qfrag 4MB | 8: Kfrag 4MB | 12: Vfrag 4MB
//   16: Tfb 4MB | 20: Trb 4MB | 24: wt 3.5MB | 28: Mfrag 4MB | 32: Zinv 32KB
// ---------------------------------------------------------------------------
extern "C" void kernel_launch(void* const* d_in, const int* in_sizes, int n_in,
                              void* d_out, int out_size, void* d_ws, size_t ws_size,
                              hipStream_t stream) {
  const float* x   = (const float*)d_in[0];
  const float* Wq  = (const float*)d_in[1];
  const float* bq  = (const float*)d_in[2];
  const float* Wk  = (const float*)d_in[3];
  const float* bk  = (const float*)d_in[4];
  const float* Wv  = (const float*)d_in[5];
  const float* bv  = (const float*)d_in[6];
  const float* cw  = (const float*)d_in[7];
  const float* cb  = (const float*)d_in[8];
  const float* Wfh = (const float*)d_in[9];
  const float* bfh = (const float*)d_in[10];
  const float* Wfg = (const float*)d_in[11];
  const float* bfg = (const float*)d_in[12];
  const float* Wrh = (const float*)d_in[13];
  const float* brh = (const float*)d_in[14];
  const float* Wrg = (const float*)d_in[15];
  const float* brg = (const float*)d_in[16];

  char* ws = (char*)d_ws;
  const size_t MB = 1024 * 1024;
  unsigned short* xb    = (unsigned short*)(ws + 0 * MB);
  unsigned short* Qfrag = (unsigned short*)(ws + 4 * MB);
  unsigned short* Kfrag = (unsigned short*)(ws + 8 * MB);
  unsigned short* Vfrag = (unsigned short*)(ws + 12 * MB);
  unsigned short* Tfb   = (unsigned short*)(ws + 16 * MB);
  unsigned short* Trb   = (unsigned short*)(ws + 20 * MB);
  unsigned short* wt    = (unsigned short*)(ws + 24 * MB);
  unsigned int*   Mfrag = (unsigned int*)(ws + 28 * MB);
  float*          Zinv  = (float*)(ws + 32 * MB);
  const size_t WSZ = 512 * 512;

  prep_kernel<<<512, 256, 0, stream>>>(x, Wq, Wk, Wv, Wfh, Wfg, Wrh, Wrg, xb, wt);
  qkv_kernel<<<dim3(8, 64), 256, 0, stream>>>(xb, wt + 0 * WSZ, wt + 1 * WSZ, wt + 2 * WSZ,
                                              bq, bk, bv, Qfrag, Kfrag, Vfrag);
  zgate_kernel<<<dim3(4, 64), 512, 0, stream>>>(Qfrag, Kfrag, cw, cb, Mfrag, Zinv);
  pv_kernel<<<dim3(8, 128), 256, 0, stream>>>(Qfrag, Kfrag, Vfrag, Mfrag, Zinv, Tfb, Trb);
  final_kernel<<<dim3(8, 128), 256, 0, stream>>>(Tfb, Trb, wt + 3 * WSZ, wt + 4 * WSZ,
                                                 wt + 5 * WSZ, wt + 6 * WSZ,
                                                 bfh, bfg, brh, brg, (float*)d_out);
}

// Round 2
// 178.258 us; speedup vs baseline: 1.0960x; 1.0091x over previous
//
#include <hip/hip_runtime.h>
#include <hip/hip_bf16.h>
#include <stdint.h>

typedef short bf16x8 __attribute__((ext_vector_type(8)));
typedef float f32x4 __attribute__((ext_vector_type(4)));

__device__ __forceinline__ unsigned short f2bf(float f) {
  union { float f; unsigned int u; } v;
  v.f = f;
  unsigned int u = v.u;
  u = (u + 0x7fffu + ((u >> 16) & 1u)) >> 16;  // RNE
  return (unsigned short)u;
}

// HW packed f32->bf16 RNE conversion (T12 recipe; bit-identical to f2bf).
__device__ __forceinline__ unsigned int cvt_pk_bf16(float lo, float hi) {
  unsigned int r;
  asm("v_cvt_pk_bf16_f32 %0, %1, %2" : "=v"(r) : "v"(lo), "v"(hi));
  return r;
}

typedef union { bf16x8 v; unsigned int u[4]; } frag_u;

// global->LDS async copy, 16B per lane.
__device__ __forceinline__ void gload16(const void* g, void* lds) {
  __builtin_amdgcn_global_load_lds(
      (const __attribute__((address_space(1))) unsigned int*)(unsigned long long)g,
      (__attribute__((address_space(3))) unsigned int*)(unsigned long long)(unsigned)(unsigned long long)lds,
      16, 0, 0);
}

__device__ __forceinline__ bf16x8 lds_frag(const unsigned short* t, int row, int ch4q) {
  return *(const bf16x8*)(t + row * 64 + ((ch4q ^ (row & 7)) << 3));
}

// Fragment layouts (element = short unless noted):
//  Qfrag/Kfrag[b][t16][h][sub][lane]: ((b*64+t16)*8192) + h*1024 + sub*512 + lane*8
//  Vfrag PAIRED [b][h][ktp][dm][lane][8]: (b*8+h)*65536 + (ktp*4+dm)*512 + lane*8
//  Mfrag (u32) PAIRED [b][qt][ktp][lane][2]: (b*64+qt)*4096 + ktp*128 + lane*2 + half
//  Zinv  [b][qt][h][q]: ((b*64+qt)*8+h)*16 + q   (precomputed 1/Z)

// ---------------------------------------------------------------------------
// Kernel 1: prep — x -> bf16 (blocks 0..255, dispatched FIRST so the
// latency-bound convert isn't serialized behind the transpose wavefront),
// 7 weights -> transposed bf16 (blocks 256..703).
// ---------------------------------------------------------------------------
__global__ __launch_bounds__(256) void prep_kernel(
    const float* __restrict__ x,
    const float* __restrict__ Wq, const float* __restrict__ Wk, const float* __restrict__ Wv,
    const float* __restrict__ Wfh, const float* __restrict__ Wfg,
    const float* __restrict__ Wrh, const float* __restrict__ Wrg,
    unsigned short* __restrict__ xb, unsigned short* __restrict__ wt) {
  int bid = blockIdx.x;
  int tid = threadIdx.x;
  if (bid < 256) {
    const float4* xi = (const float4*)x;
#pragma unroll
    for (int rep = 0; rep < 8; rep++) {
      int i = bid * 256 + tid + rep * 65536;
      float4 v = xi[i];
      uint2 u;
      u.x = cvt_pk_bf16(v.x, v.y);
      u.y = cvt_pk_bf16(v.z, v.w);
      *(uint2*)&xb[(size_t)i * 4] = u;
    }
  } else {
    __shared__ float tile[64][65];
    int t = bid - 256;
    int mat = t >> 6;
    t &= 63;
    int tr = (t >> 3) * 64, tc = (t & 7) * 64;
    const float* W = (mat == 0) ? Wq : (mat == 1) ? Wk : (mat == 2) ? Wv
                   : (mat == 3) ? Wfh : (mat == 4) ? Wfg : (mat == 5) ? Wrh : Wrg;
    unsigned short* Wt = wt + (size_t)mat * 512 * 512;
    for (int rep = 0; rep < 16; rep++) {
      int idx = rep * 256 + tid;
      int r = idx >> 6, c = idx & 63;
      tile[r][c] = W[(tr + r) * 512 + tc + c];
    }
    __syncthreads();
    for (int rep = 0; rep < 16; rep++) {
      int idx = rep * 256 + tid;
      int r = idx >> 6, c = idx & 63;
      Wt[(tc + r) * 512 + tr + c] = f2bf(tile[c][r]);
    }
  }
}

// ---------------------------------------------------------------------------
// Kernel 2: QKV projection, LDS-staged GEMM; epilogue emits fragment layouts
// (Qfrag/Kfrag, pair-packed Vfrag). grid (8 nb = head, 64 mt), 256 threads.
// LDS: staging buffers (32KB) UNIONED with the epilogue st buffer (27.6KB)
// -> 32KB total -> 4 blocks/CU (was 60KB -> 2 blocks/CU).
// ---------------------------------------------------------------------------
__global__ __launch_bounds__(256, 3) void qkv_kernel(
    const unsigned short* __restrict__ xb,
    const unsigned short* __restrict__ wtq, const unsigned short* __restrict__ wtk,
    const unsigned short* __restrict__ wtv,
    const float* __restrict__ bq, const float* __restrict__ bk, const float* __restrict__ bv,
    unsigned short* __restrict__ Qfrag, unsigned short* __restrict__ Kfrag,
    unsigned short* __restrict__ Vfrag) {
  __shared__ __attribute__((aligned(16))) unsigned short smem[16384];  // 32 KB
  unsigned short* As = smem;                 // [64*64]
  unsigned short* Bq = smem + 4096;
  unsigned short* Bk = smem + 8192;
  unsigned short* Bv = smem + 12288;
  unsigned short* st0 = smem;                // [64*72] each, epilogue only
  unsigned short* st1 = smem + 4608;
  unsigned short* st2 = smem + 9216;
  const int m0 = blockIdx.y * 64, n0 = blockIdx.x * 64;
  const int tid = threadIdx.x, w = tid >> 6, lane = tid & 63;
  const int c = lane & 15, quad = lane >> 4;
  const int wm = w & 1, wn = w >> 1;
  const int rsel = lane >> 3, csel = lane & 7;
  const int sc = csel ^ rsel;
  const char* Ag  = (const char*)xb  + (size_t)(m0 + w * 16 + rsel) * 1024 + sc * 16;
  const char* Bgq = (const char*)wtq + (size_t)(n0 + w * 16 + rsel) * 1024 + sc * 16;
  const char* Bgk = (const char*)wtk + (size_t)(n0 + w * 16 + rsel) * 1024 + sc * 16;
  const char* Bgv = (const char*)wtv + (size_t)(n0 + w * 16 + rsel) * 1024 + sc * 16;
  unsigned short* lA = &As[w * 1024];
  unsigned short* lQ = &Bq[w * 1024];
  unsigned short* lK = &Bk[w * 1024];
  unsigned short* lV = &Bv[w * 1024];

  f32x4 acc[3][2][2];
  f32x4 z4 = {0.f, 0.f, 0.f, 0.f};
#pragma unroll
  for (int o = 0; o < 3; o++)
#pragma unroll
    for (int i = 0; i < 2; i++)
#pragma unroll
      for (int j = 0; j < 2; j++) acc[o][i][j] = z4;

  for (int ks = 0; ks < 8; ks++) {
    if (ks) __syncthreads();
    const int kb = ks * 128;
    gload16(Ag + kb, lA);        gload16(Ag + kb + 8192, lA + 512);
    gload16(Bgq + kb, lQ);       gload16(Bgq + kb + 8192, lQ + 512);
    gload16(Bgk + kb, lK);       gload16(Bgk + kb + 8192, lK + 512);
    gload16(Bgv + kb, lV);       gload16(Bgv + kb + 8192, lV + 512);
    __syncthreads();
#pragma unroll
    for (int ch = 0; ch < 2; ch++) {
      const int cq = ch * 4 + quad;
      bf16x8 a0 = lds_frag(As, wm * 32 + c, cq);
      bf16x8 a1 = lds_frag(As, wm * 32 + 16 + c, cq);
#pragma unroll
      for (int nt = 0; nt < 2; nt++) {
        const int rb = wn * 32 + nt * 16 + c;
        bf16x8 fq = lds_frag(Bq, rb, cq);
        bf16x8 fk = lds_frag(Bk, rb, cq);
        bf16x8 fv = lds_frag(Bv, rb, cq);
        acc[0][0][nt] = __builtin_amdgcn_mfma_f32_16x16x32_bf16(a0, fq, acc[0][0][nt], 0, 0, 0);
        acc[0][1][nt] = __builtin_amdgcn_mfma_f32_16x16x32_bf16(a1, fq, acc[0][1][nt], 0, 0, 0);
        acc[1][0][nt] = __builtin_amdgcn_mfma_f32_16x16x32_bf16(a0, fk, acc[1][0][nt], 0, 0, 0);
        acc[1][1][nt] = __builtin_amdgcn_mfma_f32_16x16x32_bf16(a1, fk, acc[1][1][nt], 0, 0, 0);
        acc[2][0][nt] = __builtin_amdgcn_mfma_f32_16x16x32_bf16(a0, fv, acc[2][0][nt], 0, 0, 0);
        acc[2][1][nt] = __builtin_amdgcn_mfma_f32_16x16x32_bf16(a1, fv, acc[2][1][nt], 0, 0, 0);
      }
    }
  }
  __syncthreads();  // staging buffers -> st reuse hazard

  // stage: st0=Q[t][d], st1=K[t][d], st2=V[d][t]
#pragma unroll
  for (int ms = 0; ms < 2; ms++)
#pragma unroll
    for (int nt = 0; nt < 2; nt++) {
      int n_l = wn * 32 + nt * 16 + c;
      int n = n0 + n_l;
      float biasq = bq[n], biask = bk[n], biasv = bv[n];
#pragma unroll
      for (int r = 0; r < 4; r++) {
        int m_l = wm * 32 + ms * 16 + quad * 4 + r;
        st0[m_l * 72 + n_l] = f2bf((acc[0][ms][nt][r] + biasq) * 0.125f);
        st1[m_l * 72 + n_l] = f2bf(acc[1][ms][nt][r] + biask);
        st2[n_l * 72 + m_l] = f2bf(acc[2][ms][nt][r] + biasv);
      }
    }
  __syncthreads();

  {
    const int h = n0 >> 6;
    const int bb = m0 >> 10, t0b = (m0 & 1023) >> 4;
#pragma unroll
    for (int sub = 0; sub < 2; sub++) {
      uint4 vq = *(uint4*)&st0[(w * 16 + c) * 72 + sub * 32 + quad * 8];
      uint4 vk = *(uint4*)&st1[(w * 16 + c) * 72 + sub * 32 + quad * 8];
      size_t base = (size_t)((bb * 64 + t0b + w) * 8192) + h * 1024 + sub * 512 + lane * 8;
      *(uint4*)&Qfrag[base] = vq;
      *(uint4*)&Kfrag[base] = vk;
    }
    // pair-packed V fragments: kt = t0b + w; half = kt&1 selects shorts 0..3/4..7
    const int ktq = t0b + w;
    const int ktp = ktq >> 1, half = ktq & 1;
#pragma unroll
    for (int dm = 0; dm < 4; dm++) {
      uint2 vv = *(uint2*)&st2[(dm * 16 + c) * 72 + w * 16 + quad * 4];
      size_t base = (size_t)(bb * 8 + h) * 65536 + (size_t)(ktp * 4 + dm) * 512
                  + lane * 8 + half * 4;
      *(uint2*)&Vfrag[base] = vv;
    }
  }
}

// ---------------------------------------------------------------------------
// Kernel 3: zgate — FUSED softmax-denominator + gate mask.
// grid (4 b, 64 qt16), 512 thr = 8 waves; wave w owns kt = 8w..8w+7 (128 k).
// ---------------------------------------------------------------------------
__global__ __launch_bounds__(512, 4) void zgate_kernel(
    const unsigned short* __restrict__ Qfrag, const unsigned short* __restrict__ Kfrag,
    const float* __restrict__ conv_w, const float* __restrict__ conv_b,
    unsigned int* __restrict__ Mfrag, float* __restrict__ Zinv) {
  const int b = blockIdx.x, qt = blockIdx.y;
  const int tid = threadIdx.x, w = tid >> 6, lane = tid & 63;
  const int c = lane & 15, quad = lane >> 4;
  __shared__ float zbuf[8][16];

  f32x4 z4 = {0.f, 0.f, 0.f, 0.f};
  const float cb = conv_b[0];
  const size_t qbase = (size_t)((b * 64 + qt) * 8192) + lane * 8;
  const int kt0 = w * 8;
  const size_t kb0 = (size_t)((b * 64 + kt0) * 8192) + lane * 8;

  f32x4 g[8];
#pragma unroll
  for (int j = 0; j < 8; j++) g[j] = {cb, cb, cb, cb};

  for (int h = 0; h < 8; h++) {
    bf16x8 qf0 = *(const bf16x8*)&Qfrag[qbase + h * 1024];
    bf16x8 qf1 = *(const bf16x8*)&Qfrag[qbase + h * 1024 + 512];
    f32x4 p[8];
    float zh = 0.f;
#pragma unroll
    for (int j = 0; j < 8; j++) {
      const size_t kb = kb0 + (size_t)j * 8192 + h * 1024;
      bf16x8 kf0 = *(const bf16x8*)&Kfrag[kb];
      bf16x8 kf1 = *(const bf16x8*)&Kfrag[kb + 512];
      f32x4 s = __builtin_amdgcn_mfma_f32_16x16x32_bf16(kf0, qf0, z4, 0, 0, 0);
      s = __builtin_amdgcn_mfma_f32_16x16x32_bf16(kf1, qf1, s, 0, 0, 0);
      p[j][0] = __expf(s[0]); p[j][1] = __expf(s[1]);
      p[j][2] = __expf(s[2]); p[j][3] = __expf(s[3]);
      zh += (p[j][0] + p[j][1]) + (p[j][2] + p[j][3]);
    }
    // wave-local rowsum over k (rows): lanes differing in bits 4/5 share q=c
    zh += __shfl_xor(zh, 16); zh += __shfl_xor(zh, 32);
    __syncthreads();                 // prev h's zbuf reads complete
    if (quad == 0) zbuf[w][c] = zh;
    __syncthreads();                 // all wave partials visible
    float Z = ((zbuf[0][c] + zbuf[1][c]) + (zbuf[2][c] + zbuf[3][c]))
            + ((zbuf[4][c] + zbuf[5][c]) + (zbuf[6][c] + zbuf[7][c]));
    const float izq = 1.0f / Z;
    const float cwz = conv_w[h] * izq;
    if (w == 0 && quad == 0)
      Zinv[(size_t)((b * 64 + qt) * 8 + h) * 16 + c] = izq;
#pragma unroll
    for (int j = 0; j < 8; j++) {
      g[j][0] += cwz * p[j][0]; g[j][1] += cwz * p[j][1];
      g[j][2] += cwz * p[j][2]; g[j][3] += cwz * p[j][3];
    }
  }

  // masks from sign(G): bit0 = M_f (logit<=0), bit1 = M_r (logit>=0);
  // pair-packed per ktp exactly as pv expects.
#pragma unroll
  for (int j = 0; j < 4; j++) {
    unsigned int p0 = 0, p1 = 0;
#pragma unroll
    for (int r = 0; r < 4; r++) {
      p0 |= ((g[2 * j][r] <= 0.f ? 1u : 0u) | (g[2 * j][r] >= 0.f ? 2u : 0u)) << (8 * r);
      p1 |= ((g[2 * j + 1][r] <= 0.f ? 1u : 0u) | (g[2 * j + 1][r] >= 0.f ? 2u : 0u)) << (8 * r);
    }
    const int ktp = w * 4 + j;
    uint2 mm; mm.x = p0; mm.y = p1;
    *(uint2*)&Mfrag[(size_t)(b * 64 + qt) * 4096 + (size_t)ktp * 128 + lane * 2] = mm;
  }
}

// ---------------------------------------------------------------------------
// Kernel 5: pv — grid (8 h, 128 = b*32+qb), 256 thr = 4 waves.
// Pack path now via v_cvt_pk_bf16_f32 (1 op/pair vs ~9 for bit-twiddle).
// ---------------------------------------------------------------------------
__global__ __launch_bounds__(256, 4) void pv_kernel(
    const unsigned short* __restrict__ Qfrag, const unsigned short* __restrict__ Kfrag,
    const unsigned short* __restrict__ Vfrag,
    const unsigned int* __restrict__ Mfrag, const float* __restrict__ Zinv,
    unsigned short* __restrict__ Tfb, unsigned short* __restrict__ Trb) {
  const int h = blockIdx.x;
  const int b = blockIdx.y >> 5, qb = blockIdx.y & 31;
  const int tid = threadIdx.x, w = tid >> 6, lane = tid & 63;
  const int c = lane & 15, quad = lane >> 4;
  const int qloc = w & 1, kh = w >> 1;
  const int qt = qb * 2 + qloc;

  __shared__ __attribute__((aligned(16))) float red[2][4][256][4];  // 32 KB, reused
  __shared__ float zb[2][2][16];

  f32x4 z4 = {0.f, 0.f, 0.f, 0.f};
  const size_t qbase = (size_t)((b * 64 + qt) * 8192) + h * 1024 + lane * 8;
  bf16x8 qf0 = *(const bf16x8*)&Qfrag[qbase];
  bf16x8 qf1 = *(const bf16x8*)&Qfrag[qbase + 512];
  const float invZ = Zinv[(size_t)((b * 64 + qt) * 8 + h) * 16 + c];
  const size_t mbase = (size_t)(b * 64 + qt) * 4096 + lane * 2;
  const size_t vb0 = (size_t)(b * 8 + h) * 65536 + lane * 8;

  frag_u ones;
  ones.u[0] = 0x3F803F80u; ones.u[1] = 0x3F803F80u;
  ones.u[2] = 0x3F803F80u; ones.u[3] = 0x3F803F80u;

  f32x4 accf[4], accr[4];
#pragma unroll
  for (int i = 0; i < 4; i++) { accf[i] = z4; accr[i] = z4; }
  f32x4 acc_zf = z4, acc_zr = z4;

#pragma unroll 2
  for (int ip = 0; ip < 16; ip++) {
    const int ktp = kh * 16 + ip;
    const int kta = ktp * 2, ktb = kta + 1;
    const size_t kba = (size_t)((b * 64 + kta) * 8192) + h * 1024 + lane * 8;
    const size_t kbb = (size_t)((b * 64 + ktb) * 8192) + h * 1024 + lane * 8;
    bf16x8 ka0 = *(const bf16x8*)&Kfrag[kba];
    bf16x8 ka1 = *(const bf16x8*)&Kfrag[kba + 512];
    bf16x8 kb0 = *(const bf16x8*)&Kfrag[kbb];
    bf16x8 kb1 = *(const bf16x8*)&Kfrag[kbb + 512];
    f32x4 sa = __builtin_amdgcn_mfma_f32_16x16x32_bf16(ka0, qf0, z4, 0, 0, 0);
    sa = __builtin_amdgcn_mfma_f32_16x16x32_bf16(ka1, qf1, sa, 0, 0, 0);
    f32x4 sb = __builtin_amdgcn_mfma_f32_16x16x32_bf16(kb0, qf0, z4, 0, 0, 0);
    sb = __builtin_amdgcn_mfma_f32_16x16x32_bf16(kb1, qf1, sb, 0, 0, 0);
    const uint2 mp = *(const uint2*)&Mfrag[mbase + (size_t)ktp * 128];
    float ea[4], eb[4];
#pragma unroll
    for (int r = 0; r < 4; r++) {
      ea[r] = __expf(__expf(sa[r]) * invZ);
      eb[r] = __expf(__expf(sb[r]) * invZ);
    }
    frag_u pF, pR;
    {
      float f0 = (mp.x & 0x1u)        ? ea[0] : 1.f;
      float f1 = (mp.x & 0x100u)      ? ea[1] : 1.f;
      float f2 = (mp.x & 0x10000u)    ? ea[2] : 1.f;
      float f3 = (mp.x & 0x1000000u)  ? ea[3] : 1.f;
      float f4 = (mp.y & 0x1u)        ? eb[0] : 1.f;
      float f5 = (mp.y & 0x100u)      ? eb[1] : 1.f;
      float f6 = (mp.y & 0x10000u)    ? eb[2] : 1.f;
      float f7 = (mp.y & 0x1000000u)  ? eb[3] : 1.f;
      pF.u[0] = cvt_pk_bf16(f0, f1);
      pF.u[1] = cvt_pk_bf16(f2, f3);
      pF.u[2] = cvt_pk_bf16(f4, f5);
      pF.u[3] = cvt_pk_bf16(f6, f7);
      float r0 = (mp.x & 0x2u)        ? ea[0] : 1.f;
      float r1 = (mp.x & 0x200u)      ? ea[1] : 1.f;
      float r2 = (mp.x & 0x20000u)    ? ea[2] : 1.f;
      float r3 = (mp.x & 0x2000000u)  ? ea[3] : 1.f;
      float r4 = (mp.y & 0x2u)        ? eb[0] : 1.f;
      float r5 = (mp.y & 0x200u)      ? eb[1] : 1.f;
      float r6 = (mp.y & 0x20000u)    ? eb[2] : 1.f;
      float r7 = (mp.y & 0x2000000u)  ? eb[3] : 1.f;
      pR.u[0] = cvt_pk_bf16(r0, r1);
      pR.u[1] = cvt_pk_bf16(r2, r3);
      pR.u[2] = cvt_pk_bf16(r4, r5);
      pR.u[3] = cvt_pk_bf16(r6, r7);
    }
    acc_zf = __builtin_amdgcn_mfma_f32_16x16x32_bf16(ones.v, pF.v, acc_zf, 0, 0, 0);
    acc_zr = __builtin_amdgcn_mfma_f32_16x16x32_bf16(ones.v, pR.v, acc_zr, 0, 0, 0);
#pragma unroll
    for (int dm = 0; dm < 4; dm++) {
      bf16x8 vf = *(const bf16x8*)&Vfrag[vb0 + (size_t)(ktp * 4 + dm) * 512];
      accf[dm] = __builtin_amdgcn_mfma_f32_16x16x32_bf16(vf, pF.v, accf[dm], 0, 0, 0);
      accr[dm] = __builtin_amdgcn_mfma_f32_16x16x32_bf16(vf, pR.v, accr[dm], 0, 0, 0);
    }
  }

  // ---- cross-kh combine (phased through the 32KB red buffer) ----
  if (kh == 1) {
#pragma unroll
    for (int dm = 0; dm < 4; dm++) *(f32x4*)red[qloc][dm][lane] = accf[dm];
    if (lane < 16) { zb[qloc][0][lane] = acc_zf[0]; zb[qloc][1][lane] = acc_zr[0]; }
  }
  __syncthreads();
  if (kh == 0) {
#pragma unroll
    for (int dm = 0; dm < 4; dm++) accf[dm] += *(f32x4*)red[qloc][dm][lane];
  }
  __syncthreads();
  if (kh == 1) {
#pragma unroll
    for (int dm = 0; dm < 4; dm++) *(f32x4*)red[qloc][dm][lane] = accr[dm];
  }
  __syncthreads();
  uint2 outf[4], outr[4];
  if (kh == 0) {
#pragma unroll
    for (int dm = 0; dm < 4; dm++) accr[dm] += *(f32x4*)red[qloc][dm][lane];
    const float zf = acc_zf[0] + zb[qloc][0][c];
    const float zr = acc_zr[0] + zb[qloc][1][c];
    const float izf = 1.0f / zf, izr = 1.0f / zr;
#pragma unroll
    for (int dm = 0; dm < 4; dm++) {
      outf[dm].x = cvt_pk_bf16(accf[dm][0] * izf, accf[dm][1] * izf);
      outf[dm].y = cvt_pk_bf16(accf[dm][2] * izf, accf[dm][3] * izf);
      outr[dm].x = cvt_pk_bf16(accr[dm][0] * izr, accr[dm][1] * izr);
      outr[dm].y = cvt_pk_bf16(accr[dm][2] * izr, accr[dm][3] * izr);
    }
  }
  __syncthreads();
  unsigned short* ts = (unsigned short*)red;  // 64 rows x 72 = 9.2 KB < 32 KB
  if (kh == 0) {
    const int qrow = qloc * 16 + c;
#pragma unroll
    for (int dm = 0; dm < 4; dm++) {
      *(uint2*)&ts[qrow * 72 + dm * 16 + quad * 4] = outf[dm];
      *(uint2*)&ts[(32 + qrow) * 72 + dm * 16 + quad * 4] = outr[dm];
    }
  }
  __syncthreads();
  {
    const int row = tid >> 3, seg = tid & 7;
    const size_t g = (size_t)(b * 1024 + qb * 32 + row) * 512 + h * 64 + seg * 8;
    *(uint4*)&Tfb[g] = *(uint4*)&ts[row * 72 + seg * 8];
    *(uint4*)&Trb[g] = *(uint4*)&ts[(32 + row) * 72 + seg * 8];
  }
}

// ---------------------------------------------------------------------------
// Kernel 6: final — LDS-staged fused 4-GEMM + gate combine.
// grid (8 nb, 128 mt32): 32m x 64n tiles, LDS 40 KB -> 4 blocks/CU.
// ---------------------------------------------------------------------------
__global__ __launch_bounds__(256, 4) void final_kernel(
    const unsigned short* __restrict__ Tfb, const unsigned short* __restrict__ Trb,
    const unsigned short* __restrict__ wfh, const unsigned short* __restrict__ wfg,
    const unsigned short* __restrict__ wrh, const unsigned short* __restrict__ wrg,
    const float* __restrict__ bfh, const float* __restrict__ bfg,
    const float* __restrict__ brh, const float* __restrict__ brg,
    float* __restrict__ out) {
  __shared__ unsigned short Atf[32 * 64];
  __shared__ unsigned short Atr[32 * 64];
  __shared__ unsigned short Bfh[64 * 64];
  __shared__ unsigned short Bfg[64 * 64];
  __shared__ unsigned short Brh[64 * 64];
  __shared__ unsigned short Brg[64 * 64];
  const int m0 = blockIdx.y * 32, n0 = blockIdx.x * 64;
  const int tid = threadIdx.x, w = tid >> 6, lane = tid & 63;
  const int c = lane & 15, quad = lane >> 4;
  const int wm = w & 1, wn = w >> 1;
  const int rsel = lane >> 3, csel = lane & 7;
  const int sc = csel ^ rsel;
  // A tiles: wave stages 8 rows (1 gload16); B tiles: 16 rows (2 gload16).
  const char* Agf = (const char*)Tfb + (size_t)(m0 + w * 8 + rsel) * 1024 + sc * 16;
  const char* Agr = (const char*)Trb + (size_t)(m0 + w * 8 + rsel) * 1024 + sc * 16;
  const char* Bg0 = (const char*)wfh + (size_t)(n0 + w * 16 + rsel) * 1024 + sc * 16;
  const char* Bg1 = (const char*)wfg + (size_t)(n0 + w * 16 + rsel) * 1024 + sc * 16;
  const char* Bg2 = (const char*)wrh + (size_t)(n0 + w * 16 + rsel) * 1024 + sc * 16;
  const char* Bg3 = (const char*)wrg + (size_t)(n0 + w * 16 + rsel) * 1024 + sc * 16;
  unsigned short* lAf = &Atf[w * 512];
  unsigned short* lAr = &Atr[w * 512];
  unsigned short* l0 = &Bfh[w * 1024];
  unsigned short* l1 = &Bfg[w * 1024];
  unsigned short* l2 = &Brh[w * 1024];
  unsigned short* l3 = &Brg[w * 1024];

  f32x4 acc[4][2];  // [mat][nt]
  f32x4 z4 = {0.f, 0.f, 0.f, 0.f};
#pragma unroll
  for (int o = 0; o < 4; o++)
#pragma unroll
    for (int j = 0; j < 2; j++) acc[o][j] = z4;

  for (int ks = 0; ks < 8; ks++) {
    if (ks) __syncthreads();
    const int kb = ks * 128;
    gload16(Agf + kb, lAf);
    gload16(Agr + kb, lAr);
    gload16(Bg0 + kb, l0);   gload16(Bg0 + kb + 8192, l0 + 512);
    gload16(Bg1 + kb, l1);   gload16(Bg1 + kb + 8192, l1 + 512);
    gload16(Bg2 + kb, l2);   gload16(Bg2 + kb + 8192, l2 + 512);
    gload16(Bg3 + kb, l3);   gload16(Bg3 + kb + 8192, l3 + 512);
    __syncthreads();
#pragma unroll
    for (int ch = 0; ch < 2; ch++) {
      const int cq = ch * 4 + quad;
      bf16x8 af = lds_frag(Atf, wm * 16 + c, cq);
      bf16x8 ar = lds_frag(Atr, wm * 16 + c, cq);
#pragma unroll
      for (int nt = 0; nt < 2; nt++) {
        const int rb = wn * 32 + nt * 16 + c;
        bf16x8 f0 = lds_frag(Bfh, rb, cq);
        bf16x8 f1 = lds_frag(Bfg, rb, cq);
        bf16x8 f2 = lds_frag(Brh, rb, cq);
        bf16x8 f3 = lds_frag(Brg, rb, cq);
        acc[0][nt] = __builtin_amdgcn_mfma_f32_16x16x32_bf16(af, f0, acc[0][nt], 0, 0, 0);
        acc[1][nt] = __builtin_amdgcn_mfma_f32_16x16x32_bf16(af, f1, acc[1][nt], 0, 0, 0);
        acc[2][nt] = __builtin_amdgcn_mfma_f32_16x16x32_bf16(ar, f2, acc[2][nt], 0, 0, 0);
        acc[3][nt] = __builtin_amdgcn_mfma_f32_16x16x32_bf16(ar, f3, acc[3][nt], 0, 0, 0);
      }
    }
  }

#pragma unroll
  for (int nt = 0; nt < 2; nt++) {
    int n = n0 + wn * 32 + nt * 16 + c;
    float b0 = bfh[n], b1 = bfg[n], b2 = brh[n], b3 = brg[n];
    int t0 = m0 + wm * 16 + quad * 4;
#pragma unroll
    for (int r = 0; r < 4; r++) {
      int t = t0 + r;
      float Ff = acc[0][nt][r] + b0;
      float Gf = 1.0f / (1.0f + __expf(-(acc[1][nt][r] + b1)));
      float Fr = acc[2][nt][r] + b2;
      float Gr = 1.0f / (1.0f + __expf(-(acc[3][nt][r] + b3)));
      float ef = __expf(Gf), er = __expf(Gr);
      out[(size_t)t * 512 + n] = (Ff * ef + Fr * er) / (ef + er);
    }
  }
}

// ---------------------------------------------------------------------------
// Launch. Workspace (bytes):
//   0: xb 4MB | 4: Qfrag 4MB | 8: Kfrag 4MB | 12: Vfrag 4MB
//   16: Tfb 4MB | 20: Trb 4MB | 24: wt 3.5MB | 28: Mfrag 4MB | 32: Zinv 128KB
// ---------------------------------------------------------------------------
extern "C" void kernel_launch(void* const* d_in, const int* in_sizes, int n_in,
                              void* d_out, int out_size, void* d_ws, size_t ws_size,
                              hipStream_t stream) {
  const float* x   = (const float*)d_in[0];
  const float* Wq  = (const float*)d_in[1];
  const float* bq  = (const float*)d_in[2];
  const float* Wk  = (const float*)d_in[3];
  const float* bk  = (const float*)d_in[4];
  const float* Wv  = (const float*)d_in[5];
  const float* bv  = (const float*)d_in[6];
  const float* cw  = (const float*)d_in[7];
  const float* cb  = (const float*)d_in[8];
  const float* Wfh = (const float*)d_in[9];
  const float* bfh = (const float*)d_in[10];
  const float* Wfg = (const float*)d_in[11];
  const float* bfg = (const float*)d_in[12];
  const float* Wrh = (const float*)d_in[13];
  const float* brh = (const float*)d_in[14];
  const float* Wrg = (const float*)d_in[15];
  const float* brg = (const float*)d_in[16];

  char* ws = (char*)d_ws;
  const size_t MB = 1024 * 1024;
  unsigned short* xb    = (unsigned short*)(ws + 0 * MB);
  unsigned short* Qfrag = (unsigned short*)(ws + 4 * MB);
  unsigned short* Kfrag = (unsigned short*)(ws + 8 * MB);
  unsigned short* Vfrag = (unsigned short*)(ws + 12 * MB);
  unsigned short* Tfb   = (unsigned short*)(ws + 16 * MB);
  unsigned short* Trb   = (unsigned short*)(ws + 20 * MB);
  unsigned short* wt    = (unsigned short*)(ws + 24 * MB);
  unsigned int*   Mfrag = (unsigned int*)(ws + 28 * MB);
  float*          Zinv  = (float*)(ws + 32 * MB);
  const size_t WSZ = 512 * 512;

  prep_kernel<<<704, 256, 0, stream>>>(x, Wq, Wk, Wv, Wfh, Wfg, Wrh, Wrg, xb, wt);
  qkv_kernel<<<dim3(8, 64), 256, 0, stream>>>(xb, wt + 0 * WSZ, wt + 1 * WSZ, wt + 2 * WSZ,
                                              bq, bk, bv, Qfrag, Kfrag, Vfrag);
  zgate_kernel<<<dim3(4, 64), 512, 0, stream>>>(Qfrag, Kfrag, cw, cb, Mfrag, Zinv);
  pv_kernel<<<dim3(8, 128), 256, 0, stream>>>(Qfrag, Kfrag, Vfrag, Mfrag, Zinv, Tfb, Trb);
  final_kernel<<<dim3(8, 128), 256, 0, stream>>>(Tfb, Trb, wt + 3 * WSZ, wt + 4 * WSZ,
                                                 wt + 5 * WSZ, wt + 6 * WSZ,
                                                 bfh, bfg, brh, brg, (float*)d_out);
}